// Round 11
// baseline (31.093 us; speedup 1.0000x reference)
//
#include <hip/hip_runtime.h>
#include <math.h>

// B=8, N=20, H=W=512. loss = sum(bce*valid)/cnt where the last point n with
// exp(-d2/(2*5^2)) > 0.1 (<=> d2 < 50*ln10) defines the per-pixel label.
// Single dispatch; 64 blocks x 1024 threads (64 rows each); sleep-backed
// poll on 64 stride-padded flags; single-wave zero-barrier finalize.

#define R2_THRESH 115.12925464970229f
#define HW 512
#define NPTS 20
#define NBLOCKS 64               // 8 batches * 8 chunks of 64 rows
#define NROWS 64
#define MAGIC 0x5F3C9A17u
#define FSTRIDE 4                // flags padded to 16B to spread line contention

__global__ __launch_bounds__(1024)
void pce_kernel(const float* __restrict__ y_pred,
                const int* __restrict__ point_labels,
                const float* __restrict__ point_coords,
                unsigned long long* __restrict__ slots, // [64] packed {C:hi32,S:lo32}
                unsigned* __restrict__ flags,           // [64*FSTRIDE]; != MAGIC on entry, cleared on exit
                float* __restrict__ out) {
    const int bid  = blockIdx.x;
    const int b    = bid >> 3;               // 8 chunks per batch
    const int y0   = (bid & 7) * NROWS;
    const int tid  = threadIdx.x;
    const int g    = tid >> 5;               // 32 groups of 32 lanes
    const int lane = tid & 31;

    __shared__ float s_xc[NROWS][NPTS], s_lim[NROWS][NPTS], s_lab[NROWS][NPTS];
    __shared__ int   s_x0[NROWS], s_x1[NROWS];

    // ---- per-batch point data (redundant across groups; L2-coalesced) ----
    float yc = 0.0f, xc = 0.0f, lab = 0.0f;
    if (lane < NPTS) {
        float2 cc = ((const float2*)point_coords)[b * NPTS + lane];
        yc  = cc.x * (float)HW;
        xc  = cc.y * (float)HW;
        lab = (float)point_labels[b * NPTS + lane];
    }

    // ---- setup: group g builds tables for rows 2g, 2g+1 (disjoint LDS) ----
    #pragma unroll
    for (int rr = 0; rr < 2; ++rr) {
        const int row = g * 2 + rr;
        float xlo = INFINITY, xhi = -INFINITY;
        if (lane < NPTS) {
            float dy  = (float)(y0 + row) - yc;
            float lim = R2_THRESH - dy * dy;  // lim<=0 -> dx*dx<lim never true
            s_xc[row][lane]  = xc;
            s_lim[row][lane] = lim;
            s_lab[row][lane] = lab;
            if (lim > 0.0f) {
                float s = sqrtf(lim);
                xlo = xc - s;
                xhi = xc + s;
            }
        }
        #pragma unroll
        for (int off = 16; off > 0; off >>= 1) {
            xlo = fminf(xlo, __shfl_xor(xlo, off, 32));
            xhi = fmaxf(xhi, __shfl_xor(xhi, off, 32));
        }
        if (lane == 0) {
            s_x0[row] = (int)fminf(fmaxf(floorf(xlo), 0.0f), 512.0f);
            s_x1[row] = (int)fminf(fmaxf(ceilf(xhi), -1.0f), 511.0f); // empty -> x0>x1
        }
    }
    __syncthreads();

    // ---- pixel phase: group g covers its 2 rows' bboxes ----
    float sum = 0.0f, cnt = 0.0f;
    const float* base = y_pred + (size_t)b * HW * HW;
    #pragma unroll
    for (int rr = 0; rr < 2; ++rr) {
        const int row = g * 2 + rr;
        const int x0 = s_x0[row], x1 = s_x1[row];
        const float* rp = base + (size_t)(y0 + row) * HW;
        for (int px = x0 + lane; px <= x1; px += 32) {
            float l = rp[px];                 // hoisted, overlaps tests
            const float fx = (float)px;
            float pl = 0.0f;
            bool  valid = false;
            #pragma unroll
            for (int k = 0; k < NPTS; ++k) {
                float dx = fx - s_xc[row][k];
                if (dx * dx < s_lim[row][k]) { pl = s_lab[row][k]; valid = true; } // last k wins
            }
            if (valid) {
                sum += fmaxf(l, 0.0f) - l * pl + log1pf(expf(-fabsf(l)));
                cnt += 1.0f;
            }
        }
    }

    // ---- block reduction: 16 waves ----
    #pragma unroll
    for (int off = 32; off > 0; off >>= 1) {
        sum += __shfl_down(sum, off, 64);
        cnt += __shfl_down(cnt, off, 64);
    }
    __shared__ float rs[16], rc[16];
    if ((tid & 63) == 0) { rs[tid >> 6] = sum; rc[tid >> 6] = cnt; }
    __syncthreads();
    if (tid == 0) {
        float S = 0.0f, C = 0.0f;
        #pragma unroll
        for (int i = 0; i < 16; ++i) { S += rs[i]; C += rc[i]; }
        unsigned long long w = ((unsigned long long)__float_as_uint(C) << 32)
                             | (unsigned long long)__float_as_uint(S);
        __hip_atomic_store(&slots[bid], w, __ATOMIC_RELAXED, __HIP_MEMORY_SCOPE_AGENT);
        __hip_atomic_store(&flags[bid * FSTRIDE], MAGIC, __ATOMIC_RELEASE, __HIP_MEMORY_SCOPE_AGENT);
    }
    if (bid != 0 || tid >= 64) return;

    // ---- block 0, wave 0, zero barriers: lane t polls block t's flag ----
    {
        unsigned f = 0;
        do {
            f = __hip_atomic_load(&flags[tid * FSTRIDE], __ATOMIC_ACQUIRE, __HIP_MEMORY_SCOPE_AGENT);
            if (f != MAGIC) __builtin_amdgcn_s_sleep(1);
        } while (f != MAGIC);
    }
    // same-thread acquire->relaxed: ordered
    unsigned long long w = __hip_atomic_load(&slots[tid], __ATOMIC_RELAXED, __HIP_MEMORY_SCOPE_AGENT);
    float S = __uint_as_float((unsigned)(w & 0xffffffffull));
    float C = __uint_as_float((unsigned)(w >> 32));
    #pragma unroll
    for (int off = 32; off > 0; off >>= 1) {
        S += __shfl_down(S, off, 64);
        C += __shfl_down(C, off, 64);
    }
    if (tid == 0) out[0] = (C > 0.0f) ? (S / C) : 0.0f;
    // clear my flag for the next replay (my read is done)
    __hip_atomic_store(&flags[tid * FSTRIDE], 0u, __ATOMIC_RELAXED, __HIP_MEMORY_SCOPE_AGENT);
}

extern "C" void kernel_launch(void* const* d_in, const int* in_sizes, int n_in,
                              void* d_out, int out_size, void* d_ws, size_t ws_size,
                              hipStream_t stream) {
    const float* y_pred       = (const float*)d_in[0];   // (8,1,512,512) f32
    const int*   point_labels = (const int*)d_in[1];     // (8,20) i32
    const float* point_coords = (const float*)d_in[2];   // (8,20,2) f32
    float*       out          = (float*)d_out;           // scalar f32

    char* w = (char*)d_ws;
    unsigned long long* slots = (unsigned long long*)(w);      // 64 x 8B
    unsigned*           flags = (unsigned*)(w + 512);          // 64 x 16B stride

    pce_kernel<<<NBLOCKS, 1024, 0, stream>>>(y_pred, point_labels, point_coords,
                                             slots, flags, out);
}